// Round 16
// baseline (4571.320 us; speedup 1.0000x reference)
//
#include <hip/hip_runtime.h>

typedef short short8 __attribute__((ext_vector_type(8)));
typedef float f32x4 __attribute__((ext_vector_type(4)));
typedef int int4v __attribute__((ext_vector_type(4)));

#define TT 100
#define BB 128
#define HH 2048
#define CC 100
#define NBLK 256
#define CHUNK 20
#define NCH (TT / CHUNK)        // 5 chunks
#define SLOTW 8192              // u32 per step-slot: 128 rows x 64 words

__device__ inline unsigned short f2bf(float f) {
  unsigned u = __float_as_uint(f);
  return (unsigned short)((u + 0x7FFF + ((u >> 16) & 1)) >> 16);  // RNE
}
__device__ inline float bf2f(unsigned short b) {
  return __uint_as_float((unsigned)b << 16);
}

// W[k][n] fp32 (2048x2048) -> Wt[n][k] bf16 bits (for gemm_big / W1 only)
__global__ __launch_bounds__(256) void transpose_cvt(
    const float* __restrict__ W, unsigned short* __restrict__ Wt)
{
  __shared__ float t[32][33];
  int n0 = blockIdx.x * 32, k0 = blockIdx.y * 32;
  int tx = threadIdx.x, ty = threadIdx.y;   // (32,8)
  #pragma unroll
  for (int j = 0; j < 4; ++j)
    t[ty + 8 * j][tx] = W[(size_t)(k0 + ty + 8 * j) * HH + n0 + tx];
  __syncthreads();
  #pragma unroll
  for (int j = 0; j < 4; ++j)
    Wt[(size_t)(n0 + ty + 8 * j) * HH + k0 + tx] = f2bf(t[tx][ty + 8 * j]);
}

// x fp32 -> bf16 (row-major, same layout)
__global__ __launch_bounds__(512) void cvt_x(
    const float* __restrict__ x, unsigned short* __restrict__ xb, long n8)
{
  long i = (long)blockIdx.x * blockDim.x + threadIdx.x;
  if (i >= n8) return;
  const float4* p = (const float4*)x + i * 2;
  float4 a = p[0], b = p[1];
  short8 pv;
  pv[0] = (short)f2bf(a.x); pv[1] = (short)f2bf(a.y);
  pv[2] = (short)f2bf(a.z); pv[3] = (short)f2bf(a.w);
  pv[4] = (short)f2bf(b.x); pv[5] = (short)f2bf(b.y);
  pv[6] = (short)f2bf(b.z); pv[7] = (short)f2bf(b.w);
  *(short8*)(xb + i * 8) = pv;
}

// Hoisted layer-1 GEMM, A already bf16: cur1 = xb @ W1 + b1 (bf16 out).
__global__ __launch_bounds__(256) void gemm_big_bf16(
    const unsigned short* __restrict__ Ab, const unsigned short* __restrict__ Wt,
    const float* __restrict__ bias, unsigned short* __restrict__ cur)
{
  __shared__ unsigned short As[128 * 128];   // 32KB
  __shared__ unsigned short Bs[64 * 128];    // 16KB
  const int tid = threadIdx.x;
  const int w = tid >> 6, l = tid & 63;
  const int wm = w & 1, wn = w >> 1;
  const int c16 = l & 15, g = l >> 4;
  const int n0 = blockIdx.x * 64, m0 = blockIdx.y * 128;
  f32x4 acc[4][2] = {};

  for (int k0 = 0; k0 < 2048; k0 += 128) {
    #pragma unroll
    for (int i = 0; i < 8; ++i) {
      int gg = tid + i * 256;
      int r = gg >> 4, gi = gg & 15;
      int kb = (gi * 16) ^ ((r & 7) << 4);
      const char* src = (const char*)(Ab + (size_t)(m0 + r) * HH + k0) + kb;
      *(int4v*)((char*)As + r * 256 + kb) = *(const int4v*)src;
    }
    #pragma unroll
    for (int i = 0; i < 4; ++i) {
      int gg = tid + i * 256;
      int r = gg >> 4, gi = gg & 15;
      int kb = (gi * 16) ^ ((r & 7) << 4);
      const char* bsrc = (const char*)(Wt + (size_t)(n0 + r) * HH + k0) + kb;
      *(int4v*)((char*)Bs + r * 256 + kb) = *(const int4v*)bsrc;
    }
    __syncthreads();
    #pragma unroll
    for (int kk = 0; kk < 4; ++kk) {
      int koff = (kk * 4 + g) * 16;
      short8 a[4], b[2];
      #pragma unroll
      for (int mi = 0; mi < 4; ++mi) {
        int mr = wm * 64 + mi * 16 + c16;
        a[mi] = *(short8*)((char*)As + mr * 256 + (koff ^ ((mr & 7) << 4)));
      }
      #pragma unroll
      for (int ni = 0; ni < 2; ++ni) {
        int nr = wn * 32 + ni * 16 + c16;
        b[ni] = *(short8*)((char*)Bs + nr * 256 + (koff ^ ((nr & 7) << 4)));
      }
      #pragma unroll
      for (int mi = 0; mi < 4; ++mi)
        #pragma unroll
        for (int ni = 0; ni < 2; ++ni)
          acc[mi][ni] = __builtin_amdgcn_mfma_f32_16x16x32_bf16(
              a[mi], b[ni], acc[mi][ni], 0, 0, 0);
    }
    __syncthreads();
  }
  #pragma unroll
  for (int mi = 0; mi < 4; ++mi)
    #pragma unroll
    for (int ni = 0; ni < 2; ++ni) {
      int col = n0 + wn * 32 + ni * 16 + c16;
      int rbase = m0 + wm * 64 + mi * 16 + g * 4;
      float bv = bias[col];
      #pragma unroll
      for (int j = 0; j < 4; ++j)
        cur[(size_t)(rbase + j) * HH + col] = f2bf(acc[mi][ni][j] + bv);
    }
}

// Fallback (ws too small for xb): fp32 A with inline cvt.
__global__ __launch_bounds__(256) void gemm_big_f32(
    const float* __restrict__ A, const unsigned short* __restrict__ Wt,
    const float* __restrict__ bias, unsigned short* __restrict__ cur)
{
  __shared__ unsigned short As[128 * 128];
  __shared__ unsigned short Bs[64 * 128];
  const int tid = threadIdx.x;
  const int w = tid >> 6, l = tid & 63;
  const int wm = w & 1, wn = w >> 1;
  const int c16 = l & 15, g = l >> 4;
  const int n0 = blockIdx.x * 64, m0 = blockIdx.y * 128;
  f32x4 acc[4][2] = {};

  for (int k0 = 0; k0 < 2048; k0 += 128) {
    #pragma unroll
    for (int i = 0; i < 8; ++i) {
      int gg = tid + i * 256;
      int r = gg >> 4, gi = gg & 15;
      int kb = (gi * 16) ^ ((r & 7) << 4);
      const float* src = A + (size_t)(m0 + r) * HH + k0 + (kb >> 1);
      float4 f0 = *(const float4*)src, f1 = *(const float4*)(src + 4);
      short8 pv;
      pv[0] = (short)f2bf(f0.x); pv[1] = (short)f2bf(f0.y);
      pv[2] = (short)f2bf(f0.z); pv[3] = (short)f2bf(f0.w);
      pv[4] = (short)f2bf(f1.x); pv[5] = (short)f2bf(f1.y);
      pv[6] = (short)f2bf(f1.z); pv[7] = (short)f2bf(f1.w);
      *(int4v*)((char*)As + r * 256 + kb) = *(int4v*)&pv;
    }
    #pragma unroll
    for (int i = 0; i < 4; ++i) {
      int gg = tid + i * 256;
      int r = gg >> 4, gi = gg & 15;
      int kb = (gi * 16) ^ ((r & 7) << 4);
      const char* bsrc = (const char*)(Wt + (size_t)(n0 + r) * HH + k0) + kb;
      *(int4v*)((char*)Bs + r * 256 + kb) = *(const int4v*)bsrc;
    }
    __syncthreads();
    #pragma unroll
    for (int kk = 0; kk < 4; ++kk) {
      int koff = (kk * 4 + g) * 16;
      short8 a[4], b[2];
      #pragma unroll
      for (int mi = 0; mi < 4; ++mi) {
        int mr = wm * 64 + mi * 16 + c16;
        a[mi] = *(short8*)((char*)As + mr * 256 + (koff ^ ((mr & 7) << 4)));
      }
      #pragma unroll
      for (int ni = 0; ni < 2; ++ni) {
        int nr = wn * 32 + ni * 16 + c16;
        b[ni] = *(short8*)((char*)Bs + nr * 256 + (koff ^ ((nr & 7) << 4)));
      }
      #pragma unroll
      for (int mi = 0; mi < 4; ++mi)
        #pragma unroll
        for (int ni = 0; ni < 2; ++ni)
          acc[mi][ni] = __builtin_amdgcn_mfma_f32_16x16x32_bf16(
              a[mi], b[ni], acc[mi][ni], 0, 0, 0);
    }
    __syncthreads();
  }
  #pragma unroll
  for (int mi = 0; mi < 4; ++mi)
    #pragma unroll
    for (int ni = 0; ni < 2; ++ni) {
      int col = n0 + wn * 32 + ni * 16 + c16;
      int rbase = m0 + wm * 64 + mi * 16 + g * 4;
      float bv = bias[col];
      #pragma unroll
      for (int j = 0; j < 4; ++j)
        cur[(size_t)(rbase + j) * HH + col] = f2bf(acc[mi][ni][j] + bv);
    }
}

__global__ void init_kernel(unsigned* flags, int n)
{
  int i = blockIdx.x * blockDim.x + threadIdx.x;
  int stride = gridDim.x * blockDim.x;
  for (int j = i; j < n; j += stride) flags[j] = 0u;
}

// ---- per-WAVE dataflow sync (no block barriers; bounded spins) ----
__device__ inline void waitwave(unsigned* f, int n, unsigned val)
{
  int lane = threadIdx.x & 63;
  for (int i = lane; i < n; i += 64) {
    int guard = 0;
    while (__hip_atomic_load(&f[i * 32], __ATOMIC_ACQUIRE,
                             __HIP_MEMORY_SCOPE_AGENT) < val) {
      __builtin_amdgcn_s_sleep(2);
      if (++guard > (1 << 22)) break;   // fail loud (wrong absmax), never hang
    }
  }
  __builtin_amdgcn_fence(__ATOMIC_ACQUIRE, "agent");
}

// ---- round-14 GEMM step macros (proven 537 us configuration) ----
#define MM(WORD, HF, SIDX, ACCV) { \
    unsigned h_ = (HF) ? ((unsigned)(WORD) >> 16) : ((unsigned)(WORD) & 0xFFFFu); \
    int4v af_; \
    af_[0] = (int)(((h_ & 15u) * 0x204081u) & 0x01010101u); \
    af_[1] = (int)((((h_ >> 4) & 15u) * 0x204081u) & 0x01010101u); \
    af_[2] = (int)((((h_ >> 8) & 15u) * 0x204081u) & 0x01010101u); \
    af_[3] = (int)(((h_ >> 12) * 0x204081u) & 0x01010101u); \
    int4v bq_ = *(const int4v*)(bpan + bbase + (((SIDX) * 64) ^ bswz)); \
    ACCV = __builtin_amdgcn_mfma_i32_16x16x64_i8(af_, bq_, ACCV, 0, 0, 0); }

#define STEP8(ACV, CH, ACCV) \
    MM(ACV[CH][0], 0, CH * 8 + 0, ACCV) MM(ACV[CH][0], 1, CH * 8 + 1, ACCV) \
    MM(ACV[CH][1], 0, CH * 8 + 2, ACCV) MM(ACV[CH][1], 1, CH * 8 + 3, ACCV) \
    MM(ACV[CH][2], 0, CH * 8 + 4, ACCV) MM(ACV[CH][2], 1, CH * 8 + 5, ACCV) \
    MM(ACV[CH][3], 0, CH * 8 + 6, ACCV) MM(ACV[CH][3], 1, CH * 8 + 7, ACCV)

#define LOADN(AN, TN) { \
    const char* sb_ = (const char*)(sinb + (size_t)(TN) * SLOTW); \
    AN[0] = *(const int4v*)(sb_ + abyte + 0 * 64); \
    AN[1] = *(const int4v*)(sb_ + abyte + 1 * 64); \
    AN[2] = *(const int4v*)(sb_ + abyte + 2 * 64); \
    AN[3] = *(const int4v*)(sb_ + abyte + 3 * 64); }

#define STEPB(AC, AN, T, DOPRE) { \
    if (DOPRE) LOADN(AN, (T) + 1); \
    int4v acc0_ = {0, 0, 0, 0}, acc1_ = {0, 0, 0, 0}; \
    STEP8(AC, 0, acc0_) STEP8(AC, 1, acc0_) \
    STEP8(AC, 2, acc1_) STEP8(AC, 3, acc1_) \
    int4v accs_ = acc0_ + acc1_; \
    unsigned long long bal0_, bal1_, bal2_, bal3_; \
    { float cv_ = (float)accs_[0] * scl + bv, mo_ = memb[0]; \
      float mn_ = 0.9f * mo_ + cv_ - ((mo_ > 1.f) ? 1.f : 0.f); \
      memb[0] = mn_; bal0_ = __ballot((int)(mn_ > 1.f)); } \
    { float cv_ = (float)accs_[1] * scl + bv, mo_ = memb[1]; \
      float mn_ = 0.9f * mo_ + cv_ - ((mo_ > 1.f) ? 1.f : 0.f); \
      memb[1] = mn_; bal1_ = __ballot((int)(mn_ > 1.f)); } \
    { float cv_ = (float)accs_[2] * scl + bv, mo_ = memb[2]; \
      float mn_ = 0.9f * mo_ + cv_ - ((mo_ > 1.f) ? 1.f : 0.f); \
      memb[2] = mn_; bal2_ = __ballot((int)(mn_ > 1.f)); } \
    { float cv_ = (float)accs_[3] * scl + bv, mo_ = memb[3]; \
      float mn_ = 0.9f * mo_ + cv_ - ((mo_ > 1.f) ? 1.f : 0.f); \
      memb[3] = mn_; bal3_ = __ballot((int)(mn_ > 1.f)); } \
    if (c16 == 0) { \
      unsigned short* so_ = (unsigned short*)(soutb + (size_t)(T) * SLOTW); \
      int rb_ = w * 16 + g * 4; \
      so_[(rb_ + 0) * 128 + ppos] = (unsigned short)((bal0_ >> (g * 16)) & 0xFFFFull); \
      so_[(rb_ + 1) * 128 + ppos] = (unsigned short)((bal1_ >> (g * 16)) & 0xFFFFull); \
      so_[(rb_ + 2) * 128 + ppos] = (unsigned short)((bal2_ >> (g * 16)) & 0xFFFFull); \
      so_[(rb_ + 3) * 128 + ppos] = (unsigned short)((bal3_ >> (g * 16)) & 0xFFFFull); \
    } }

// Persistent SNN, wave-specialized: 256 blocks x 1024 thr (16 waves/CU).
// Waves 0-7 (tid<512): GEMM engine — blk<128 layer2, else layer3; free-runs
//   chunks gated only by producer flags; marks f2/f3 via LDS-counter aggregate.
// Waves 8-15: duty engine — L1-LIF (all blocks, half row) front-loaded,
//   marks f1; L3 blocks' duty waves 0-1 then run wave-local out-scan.
__global__ __launch_bounds__(1024, 4) void snn_persist(
    const unsigned short* __restrict__ cur1,
    const float* __restrict__ W2, const float* __restrict__ b2,
    const float* __restrict__ W3, const float* __restrict__ b3,
    const float* __restrict__ Wo, const float* __restrict__ bo,
    unsigned* __restrict__ s1b, unsigned* __restrict__ s2b,
    unsigned* __restrict__ s3b,
    float* __restrict__ outsum,
    unsigned* __restrict__ f1, unsigned* __restrict__ f2,
    unsigned* __restrict__ f3)
{
  __shared__ char bpan[16 * 2048];             // 32KB i8 weight panel
  __shared__ int cntG[NCH];                    // GEMM-wave completion counters
  __shared__ int cntL1[NCH];                   // duty-wave L1 counters

  const int blk = blockIdx.x, tid = threadIdx.x;
  const bool isL2 = blk < 128;
  const int panel = blk & 127;
  const int n0c = panel * 16;
  const float* Wsrc = isL2 ? W2 : W3;
  const float* bias = isL2 ? b2 : b3;

  if (tid < NCH) cntG[tid] = 0;
  else if (tid < 2 * NCH) cntL1[tid - NCH] = 0;

  float scl = 0.f, bv = 0.f;
  if (tid < 512) {
    const int l = tid & 63;
    const int c16 = l & 15, g = l >> 4;
    const int col = n0c + c16;
    // quant pass 1: per-column absmax; shfl reduce across wave
    float mx = 0.f;
    for (int s = 0; s < 32; ++s) {
      int kb = s * 64 + g * 16;
      #pragma unroll
      for (int e = 0; e < 16; ++e)
        mx = fmaxf(mx, fabsf(Wsrc[(size_t)(kb + e) * HH + col]));
    }
    mx = fmaxf(mx, __shfl_xor(mx, 16));
    mx = fmaxf(mx, __shfl_xor(mx, 32));
    scl = mx * (1.f / 127.f);
    const float rsc = (mx > 0.f) ? (127.f / mx) : 0.f;
    bv = bias[col];
    // quant pass 2: fill LDS panel (tid<512 covers all (c, kg))
    {
      int c = tid & 15, kg = tid >> 4;         // kg 0..31
      #pragma unroll
      for (int j = 0; j < 4; ++j) {
        int k16 = kg * 64 + j * 16;
        int4v q = {0, 0, 0, 0};
        #pragma unroll
        for (int e = 0; e < 16; ++e) {
          float v = Wsrc[(size_t)(k16 + e) * HH + col];
          int qi = (int)rintf(v * rsc);
          qi = qi > 127 ? 127 : (qi < -127 ? -127 : qi);
          q[e >> 2] |= (qi & 0xFF) << ((e & 3) * 8);
        }
        *(int4v*)(bpan + c * 2048 + (k16 ^ ((c & 7) << 4))) = q;
      }
    }
  }
  __syncthreads();   // bpan + counters visible to all

  if (tid < 512) {
    // =========== GEMM engine (waves 0-7) ===========
    const int w = tid >> 6, l = tid & 63;
    const int c16 = l & 15, g = l >> 4;
    const int bbase = c16 * 2048 + g * 16;
    const int bswz = (c16 & 7) << 4;
    const int ppos = ((panel >> 5) << 5) + ((panel & 3) << 3) + ((panel >> 2) & 7);
    const int arow = w * 16 + c16;
    const int abyte = arow * 256 + g * 16;
    const unsigned* sinb = isL2 ? s1b : s2b;
    unsigned* soutb = isL2 ? s2b : s3b;
    unsigned* fin = isL2 ? f1 : f2;
    const int nfin = isL2 ? 256 : 128;
    unsigned* fout = isL2 ? f2 : f3;
    f32x4 memb = {0.f, 0.f, 0.f, 0.f};

    for (int tch = 0; tch < NCH; ++tch) {
      waitwave(fin, nfin, (unsigned)(tch + 1));
      int4v A0[4], A1[4];
      LOADN(A0, tch * CHUNK);
      for (int st2 = 0; st2 < CHUNK; st2 += 2) {
        const int t0 = tch * CHUNK + st2;
        STEPB(A0, A1, t0, 1)
        STEPB(A1, A0, t0 + 1, st2 + 1 < CHUNK - 1)
      }
      if (l == 0) {
        __threadfence();                        // drain this wave's stores
        int old = atomicAdd(&cntG[tch], 1);
        if (old == 7)
          __hip_atomic_store(&fout[panel * 32], (unsigned)(tch + 1),
                             __ATOMIC_RELEASE, __HIP_MEMORY_SCOPE_AGENT);
      }
    }
  } else {
    // =========== duty engine (waves 8-15) ===========
    const int dtid = tid - 512;
    const int dw = dtid >> 6;
    const int l1row = panel;
    const int l1colbase = (blk >> 7) * 1024;
    const int l1kap = (blk >> 7) * 64 + (dtid >> 3);
    const int l1pos = (l1kap & ~31) + ((l1kap & 3) << 3) + ((l1kap >> 2) & 7);
    float m1a = 0.f, m1b = 0.f;

    // L1-LIF: all 5 chunks front-loaded
    for (int p = 0; p < NCH; ++p) {
      #pragma unroll
      for (int half = 0; half < 2; ++half) {
        unsigned cw[10];
        #pragma unroll
        for (int st = 0; st < 10; ++st) {
          int t = p * CHUNK + half * 10 + st;
          cw[st] = *((const unsigned*)(cur1 +
                     ((size_t)t * BB + l1row) * HH + l1colbase) + dtid);
        }
        #pragma unroll
        for (int st = 0; st < 10; ++st) {
          int t = p * CHUNK + half * 10 + st;
          float c0 = bf2f((unsigned short)(cw[st] & 0xFFFF));
          float c1 = bf2f((unsigned short)(cw[st] >> 16));
          float mn0 = 0.9f * m1a + c0 - ((m1a > 1.f) ? 1.f : 0.f);
          float mn1 = 0.9f * m1b + c1 - ((m1b > 1.f) ? 1.f : 0.f);
          m1a = mn0; m1b = mn1;
          unsigned v = (mn0 > 1.f ? 1u : 0u) | (mn1 > 1.f ? 2u : 0u);
          v |= ((unsigned)__shfl_xor((int)v, 1)) << 2;
          v |= ((unsigned)__shfl_xor((int)v, 2)) << 4;
          v |= ((unsigned)__shfl_xor((int)v, 4)) << 8;
          if ((dtid & 7) == 0) {
            unsigned short* so = (unsigned short*)(s1b + (size_t)t * SLOTW)
                                 + l1row * 128;
            so[l1pos] = (unsigned short)v;
          }
        }
      }
      if ((dtid & 63) == 0) {
        __threadfence();
        int old = atomicAdd(&cntL1[p], 1);
        if (old == 7)
          __hip_atomic_store(&f1[blk * 32], (unsigned)(p + 1),
                             __ATOMIC_RELEASE, __HIP_MEMORY_SCOPE_AGENT);
      }
    }

    // out-layer wave-local sparse scan: L3 blocks, duty waves 0-1
    if (!isL2 && dw < 2) {
      const int r = blk - 128;
      const int lane = dtid & 63;
      const int cbase = dw * 50;
      const int myc = cbase + lane;             // class (lane < 50)
      const float boc = (lane < 50 && myc < CC) ? bo[myc] : 0.f;
      float memo = 0.f, osumo = 0.f;
      for (int oc = 0; oc < NCH; ++oc) {
        waitwave(f3, 128, (unsigned)(oc + 1));
        #pragma unroll 1
        for (int st = 0; st < CHUNK; ++st) {
          int t = oc * CHUNK + st;
          unsigned wv = s3b[(size_t)t * SLOTW + r * 64 + lane];  // word `lane`
          unsigned long long m = __ballot((int)(wv != 0u));
          float curv = boc;
          while (m) {
            int wd = (int)__ffsll((long long)m) - 1; m &= m - 1;
            unsigned wv2 = (unsigned)__shfl((int)wv, wd);
            #pragma unroll
            for (int hf = 0; hf < 2; ++hf) {
              unsigned hv = hf ? (wv2 >> 16) : (wv2 & 0xFFFFu);
              int P = wd * 2 + hf;
              int kap = ((P >> 5) << 5) + ((P & 7) << 2) + ((P >> 3) & 3);
              while (hv) {
                int b = (int)__ffs(hv) - 1; hv &= hv - 1;
                if (lane < 50) curv += Wo[(size_t)(kap * 16 + b) * CC + myc];
              }
            }
          }
          float mo = memo;
          float mn = 0.9f * mo + curv - ((mo > 1.f) ? 1.f : 0.f);
          memo = mn;
          if (mn > 1.f) osumo += 1.f;
        }
      }
      if (lane < 50) outsum[r * CC + myc] = osumo;
    }
  }
}

extern "C" void kernel_launch(void* const* d_in, const int* in_sizes, int n_in,
                              void* d_out, int out_size, void* d_ws, size_t ws_size,
                              hipStream_t stream)
{
  const float* x  = (const float*)d_in[0];
  const float* W1 = (const float*)d_in[1];
  const float* b1 = (const float*)d_in[2];
  const float* W2 = (const float*)d_in[3];
  const float* b2 = (const float*)d_in[4];
  const float* W3 = (const float*)d_in[5];
  const float* b3 = (const float*)d_in[6];
  const float* Wo = (const float*)d_in[7];
  const float* bo = (const float*)d_in[8];
  float* out = (float*)d_out;

  // ws layout
  unsigned* flags = (unsigned*)d_ws;                       // 16384 u32 region
  unsigned* f1 = flags;                                    // 256 x stride32
  unsigned* f2 = flags + 8192;                             // 128 x stride32
  unsigned* f3 = flags + 12288;                            // 128 x stride32
  unsigned* s1b = flags + 16384;                           // TT*SLOTW each
  unsigned* s2b = s1b + (size_t)TT * SLOTW;
  unsigned* s3b = s2b + (size_t)TT * SLOTW;
  unsigned short* Wt1 = (unsigned short*)(s3b + (size_t)TT * SLOTW);  // 2048^2
  unsigned short* cur1 = Wt1 + (size_t)HH * HH;            // 12800 x 2048 bf16
  unsigned short* xb = cur1 + (size_t)TT * BB * HH;        // 12800 x 2048 bf16
  size_t need_xb = (size_t)((char*)(xb + (size_t)TT * BB * HH) - (char*)d_ws);

  hipLaunchKernelGGL(init_kernel, dim3(32), dim3(256), 0, stream, flags, 16384);
  hipLaunchKernelGGL(transpose_cvt, dim3(64, 64), dim3(32, 8), 0, stream, W1, Wt1);
  if (ws_size >= need_xb) {
    long n8 = (long)TT * BB * HH / 8;
    hipLaunchKernelGGL(cvt_x, dim3((unsigned)((n8 + 511) / 512)), dim3(512),
                       0, stream, x, xb, n8);
    hipLaunchKernelGGL(gemm_big_bf16, dim3(HH / 64, (TT * BB) / 128), dim3(256),
                       0, stream, xb, Wt1, b1, cur1);
  } else {
    hipLaunchKernelGGL(gemm_big_f32, dim3(HH / 64, (TT * BB) / 128), dim3(256),
                       0, stream, x, Wt1, b1, cur1);
  }
  hipLaunchKernelGGL(snn_persist, dim3(NBLK), dim3(1024), 0, stream,
                     cur1, W2, b2, W3, b3, Wo, bo,
                     s1b, s2b, s3b, out, f1, f2, f3);
}

// Round 17
// 4555.998 us; speedup vs baseline: 1.0034x; 1.0034x over previous
//
#include <hip/hip_runtime.h>

typedef short short8 __attribute__((ext_vector_type(8)));
typedef float f32x4 __attribute__((ext_vector_type(4)));
typedef int int4v __attribute__((ext_vector_type(4)));

#define TT 100
#define BB 128
#define HH 2048
#define CC 100
#define NBLK 256
#define CHUNK 20
#define NCH (TT / CHUNK)        // 5 chunks
#define SLOTW 8192              // u32 per step-slot: 128 rows x 64 words

__device__ inline unsigned short f2bf(float f) {
  unsigned u = __float_as_uint(f);
  return (unsigned short)((u + 0x7FFF + ((u >> 16) & 1)) >> 16);  // RNE
}
__device__ inline float bf2f(unsigned short b) {
  return __uint_as_float((unsigned)b << 16);
}

// W[k][n] fp32 (2048x2048) -> Wt[n][k] bf16 bits (for gemm_big / W1 only)
__global__ __launch_bounds__(256) void transpose_cvt(
    const float* __restrict__ W, unsigned short* __restrict__ Wt)
{
  __shared__ float t[32][33];
  int n0 = blockIdx.x * 32, k0 = blockIdx.y * 32;
  int tx = threadIdx.x, ty = threadIdx.y;   // (32,8)
  #pragma unroll
  for (int j = 0; j < 4; ++j)
    t[ty + 8 * j][tx] = W[(size_t)(k0 + ty + 8 * j) * HH + n0 + tx];
  __syncthreads();
  #pragma unroll
  for (int j = 0; j < 4; ++j)
    Wt[(size_t)(n0 + ty + 8 * j) * HH + k0 + tx] = f2bf(t[tx][ty + 8 * j]);
}

// x fp32 -> bf16 (row-major, same layout)
__global__ __launch_bounds__(512) void cvt_x(
    const float* __restrict__ x, unsigned short* __restrict__ xb, long n8)
{
  long i = (long)blockIdx.x * blockDim.x + threadIdx.x;
  if (i >= n8) return;
  const float4* p = (const float4*)x + i * 2;
  float4 a = p[0], b = p[1];
  short8 pv;
  pv[0] = (short)f2bf(a.x); pv[1] = (short)f2bf(a.y);
  pv[2] = (short)f2bf(a.z); pv[3] = (short)f2bf(a.w);
  pv[4] = (short)f2bf(b.x); pv[5] = (short)f2bf(b.y);
  pv[6] = (short)f2bf(b.z); pv[7] = (short)f2bf(b.w);
  *(short8*)(xb + i * 8) = pv;
}

// Hoisted layer-1 GEMM, A already bf16: cur1 = xb @ W1 + b1 (bf16 out).
__global__ __launch_bounds__(256) void gemm_big_bf16(
    const unsigned short* __restrict__ Ab, const unsigned short* __restrict__ Wt,
    const float* __restrict__ bias, unsigned short* __restrict__ cur)
{
  __shared__ unsigned short As[128 * 128];   // 32KB
  __shared__ unsigned short Bs[64 * 128];    // 16KB
  const int tid = threadIdx.x;
  const int w = tid >> 6, l = tid & 63;
  const int wm = w & 1, wn = w >> 1;
  const int c16 = l & 15, g = l >> 4;
  const int n0 = blockIdx.x * 64, m0 = blockIdx.y * 128;
  f32x4 acc[4][2] = {};

  for (int k0 = 0; k0 < 2048; k0 += 128) {
    #pragma unroll
    for (int i = 0; i < 8; ++i) {
      int gg = tid + i * 256;
      int r = gg >> 4, gi = gg & 15;
      int kb = (gi * 16) ^ ((r & 7) << 4);
      const char* src = (const char*)(Ab + (size_t)(m0 + r) * HH + k0) + kb;
      *(int4v*)((char*)As + r * 256 + kb) = *(const int4v*)src;
    }
    #pragma unroll
    for (int i = 0; i < 4; ++i) {
      int gg = tid + i * 256;
      int r = gg >> 4, gi = gg & 15;
      int kb = (gi * 16) ^ ((r & 7) << 4);
      const char* bsrc = (const char*)(Wt + (size_t)(n0 + r) * HH + k0) + kb;
      *(int4v*)((char*)Bs + r * 256 + kb) = *(const int4v*)bsrc;
    }
    __syncthreads();
    #pragma unroll
    for (int kk = 0; kk < 4; ++kk) {
      int koff = (kk * 4 + g) * 16;
      short8 a[4], b[2];
      #pragma unroll
      for (int mi = 0; mi < 4; ++mi) {
        int mr = wm * 64 + mi * 16 + c16;
        a[mi] = *(short8*)((char*)As + mr * 256 + (koff ^ ((mr & 7) << 4)));
      }
      #pragma unroll
      for (int ni = 0; ni < 2; ++ni) {
        int nr = wn * 32 + ni * 16 + c16;
        b[ni] = *(short8*)((char*)Bs + nr * 256 + (koff ^ ((nr & 7) << 4)));
      }
      #pragma unroll
      for (int mi = 0; mi < 4; ++mi)
        #pragma unroll
        for (int ni = 0; ni < 2; ++ni)
          acc[mi][ni] = __builtin_amdgcn_mfma_f32_16x16x32_bf16(
              a[mi], b[ni], acc[mi][ni], 0, 0, 0);
    }
    __syncthreads();
  }
  #pragma unroll
  for (int mi = 0; mi < 4; ++mi)
    #pragma unroll
    for (int ni = 0; ni < 2; ++ni) {
      int col = n0 + wn * 32 + ni * 16 + c16;
      int rbase = m0 + wm * 64 + mi * 16 + g * 4;
      float bv = bias[col];
      #pragma unroll
      for (int j = 0; j < 4; ++j)
        cur[(size_t)(rbase + j) * HH + col] = f2bf(acc[mi][ni][j] + bv);
    }
}

// Fallback (ws too small for xb): fp32 A with inline cvt.
__global__ __launch_bounds__(256) void gemm_big_f32(
    const float* __restrict__ A, const unsigned short* __restrict__ Wt,
    const float* __restrict__ bias, unsigned short* __restrict__ cur)
{
  __shared__ unsigned short As[128 * 128];
  __shared__ unsigned short Bs[64 * 128];
  const int tid = threadIdx.x;
  const int w = tid >> 6, l = tid & 63;
  const int wm = w & 1, wn = w >> 1;
  const int c16 = l & 15, g = l >> 4;
  const int n0 = blockIdx.x * 64, m0 = blockIdx.y * 128;
  f32x4 acc[4][2] = {};

  for (int k0 = 0; k0 < 2048; k0 += 128) {
    #pragma unroll
    for (int i = 0; i < 8; ++i) {
      int gg = tid + i * 256;
      int r = gg >> 4, gi = gg & 15;
      int kb = (gi * 16) ^ ((r & 7) << 4);
      const float* src = A + (size_t)(m0 + r) * HH + k0 + (kb >> 1);
      float4 f0 = *(const float4*)src, f1 = *(const float4*)(src + 4);
      short8 pv;
      pv[0] = (short)f2bf(f0.x); pv[1] = (short)f2bf(f0.y);
      pv[2] = (short)f2bf(f0.z); pv[3] = (short)f2bf(f0.w);
      pv[4] = (short)f2bf(f1.x); pv[5] = (short)f2bf(f1.y);
      pv[6] = (short)f2bf(f1.z); pv[7] = (short)f2bf(f1.w);
      *(int4v*)((char*)As + r * 256 + kb) = *(int4v*)&pv;
    }
    #pragma unroll
    for (int i = 0; i < 4; ++i) {
      int gg = tid + i * 256;
      int r = gg >> 4, gi = gg & 15;
      int kb = (gi * 16) ^ ((r & 7) << 4);
      const char* bsrc = (const char*)(Wt + (size_t)(n0 + r) * HH + k0) + kb;
      *(int4v*)((char*)Bs + r * 256 + kb) = *(const int4v*)bsrc;
    }
    __syncthreads();
    #pragma unroll
    for (int kk = 0; kk < 4; ++kk) {
      int koff = (kk * 4 + g) * 16;
      short8 a[4], b[2];
      #pragma unroll
      for (int mi = 0; mi < 4; ++mi) {
        int mr = wm * 64 + mi * 16 + c16;
        a[mi] = *(short8*)((char*)As + mr * 256 + (koff ^ ((mr & 7) << 4)));
      }
      #pragma unroll
      for (int ni = 0; ni < 2; ++ni) {
        int nr = wn * 32 + ni * 16 + c16;
        b[ni] = *(short8*)((char*)Bs + nr * 256 + (koff ^ ((nr & 7) << 4)));
      }
      #pragma unroll
      for (int mi = 0; mi < 4; ++mi)
        #pragma unroll
        for (int ni = 0; ni < 2; ++ni)
          acc[mi][ni] = __builtin_amdgcn_mfma_f32_16x16x32_bf16(
              a[mi], b[ni], acc[mi][ni], 0, 0, 0);
    }
    __syncthreads();
  }
  #pragma unroll
  for (int mi = 0; mi < 4; ++mi)
    #pragma unroll
    for (int ni = 0; ni < 2; ++ni) {
      int col = n0 + wn * 32 + ni * 16 + c16;
      int rbase = m0 + wm * 64 + mi * 16 + g * 4;
      float bv = bias[col];
      #pragma unroll
      for (int j = 0; j < 4; ++j)
        cur[(size_t)(rbase + j) * HH + col] = f2bf(acc[mi][ni][j] + bv);
    }
}

__global__ void init_kernel(unsigned* flags, int n)
{
  int i = blockIdx.x * blockDim.x + threadIdx.x;
  int stride = gridDim.x * blockDim.x;
  for (int j = i; j < n; j += stride) flags[j] = 0u;
}

// ---- per-WAVE dataflow sync (no block barriers; bounded spins) ----
__device__ inline void waitwave(unsigned* f, int n, unsigned val)
{
  int lane = threadIdx.x & 63;
  for (int i = lane; i < n; i += 64) {
    int guard = 0;
    while (__hip_atomic_load(&f[i * 32], __ATOMIC_ACQUIRE,
                             __HIP_MEMORY_SCOPE_AGENT) < val) {
      __builtin_amdgcn_s_sleep(2);
      if (++guard > (1 << 22)) break;   // fail loud (wrong absmax), never hang
    }
  }
  __builtin_amdgcn_fence(__ATOMIC_ACQUIRE, "agent");
}

// ---- round-14 GEMM step macros (proven 537 us configuration) ----
#define MM(WORD, HF, SIDX, ACCV) { \
    unsigned h_ = (HF) ? ((unsigned)(WORD) >> 16) : ((unsigned)(WORD) & 0xFFFFu); \
    int4v af_; \
    af_[0] = (int)(((h_ & 15u) * 0x204081u) & 0x01010101u); \
    af_[1] = (int)((((h_ >> 4) & 15u) * 0x204081u) & 0x01010101u); \
    af_[2] = (int)((((h_ >> 8) & 15u) * 0x204081u) & 0x01010101u); \
    af_[3] = (int)(((h_ >> 12) * 0x204081u) & 0x01010101u); \
    int4v bq_ = *(const int4v*)(bpan + bbase + (((SIDX) * 64) ^ bswz)); \
    ACCV = __builtin_amdgcn_mfma_i32_16x16x64_i8(af_, bq_, ACCV, 0, 0, 0); }

#define STEP8(ACV, CH, ACCV) \
    MM(ACV[CH][0], 0, CH * 8 + 0, ACCV) MM(ACV[CH][0], 1, CH * 8 + 1, ACCV) \
    MM(ACV[CH][1], 0, CH * 8 + 2, ACCV) MM(ACV[CH][1], 1, CH * 8 + 3, ACCV) \
    MM(ACV[CH][2], 0, CH * 8 + 4, ACCV) MM(ACV[CH][2], 1, CH * 8 + 5, ACCV) \
    MM(ACV[CH][3], 0, CH * 8 + 6, ACCV) MM(ACV[CH][3], 1, CH * 8 + 7, ACCV)

#define LOADN(AN, TN) { \
    const char* sb_ = (const char*)(sinb + (size_t)(TN) * SLOTW); \
    AN[0] = *(const int4v*)(sb_ + abyte + 0 * 64); \
    AN[1] = *(const int4v*)(sb_ + abyte + 1 * 64); \
    AN[2] = *(const int4v*)(sb_ + abyte + 2 * 64); \
    AN[3] = *(const int4v*)(sb_ + abyte + 3 * 64); }

#define STEPB(AC, AN, T, DOPRE) { \
    if (DOPRE) LOADN(AN, (T) + 1); \
    int4v acc0_ = {0, 0, 0, 0}, acc1_ = {0, 0, 0, 0}; \
    STEP8(AC, 0, acc0_) STEP8(AC, 1, acc0_) \
    STEP8(AC, 2, acc1_) STEP8(AC, 3, acc1_) \
    int4v accs_ = acc0_ + acc1_; \
    unsigned long long bal0_, bal1_, bal2_, bal3_; \
    { float cv_ = (float)accs_[0] * scl + bv, mo_ = memb[0]; \
      float mn_ = 0.9f * mo_ + cv_ - ((mo_ > 1.f) ? 1.f : 0.f); \
      memb[0] = mn_; bal0_ = __ballot((int)(mn_ > 1.f)); } \
    { float cv_ = (float)accs_[1] * scl + bv, mo_ = memb[1]; \
      float mn_ = 0.9f * mo_ + cv_ - ((mo_ > 1.f) ? 1.f : 0.f); \
      memb[1] = mn_; bal1_ = __ballot((int)(mn_ > 1.f)); } \
    { float cv_ = (float)accs_[2] * scl + bv, mo_ = memb[2]; \
      float mn_ = 0.9f * mo_ + cv_ - ((mo_ > 1.f) ? 1.f : 0.f); \
      memb[2] = mn_; bal2_ = __ballot((int)(mn_ > 1.f)); } \
    { float cv_ = (float)accs_[3] * scl + bv, mo_ = memb[3]; \
      float mn_ = 0.9f * mo_ + cv_ - ((mo_ > 1.f) ? 1.f : 0.f); \
      memb[3] = mn_; bal3_ = __ballot((int)(mn_ > 1.f)); } \
    if (c16 == 0) { \
      unsigned short* so_ = (unsigned short*)(soutb + (size_t)(T) * SLOTW); \
      int rb_ = w * 16 + g * 4; \
      so_[(rb_ + 0) * 128 + ppos] = (unsigned short)((bal0_ >> (g * 16)) & 0xFFFFull); \
      so_[(rb_ + 1) * 128 + ppos] = (unsigned short)((bal1_ >> (g * 16)) & 0xFFFFull); \
      so_[(rb_ + 2) * 128 + ppos] = (unsigned short)((bal2_ >> (g * 16)) & 0xFFFFull); \
      so_[(rb_ + 3) * 128 + ppos] = (unsigned short)((bal3_ >> (g * 16)) & 0xFFFFull); \
    } }

// Persistent SNN, wave-specialized: 256 blocks x 1024 thr (16 waves/CU).
// __launch_bounds__(1024) ONLY: backend derives VGPR cap 128 from the 16-wave
// block (round-16's ",4" made it budget 64 VGPR -> total spill).
// Waves 0-7 (tid<512): GEMM engine — blk<128 layer2, else layer3; free-runs
//   chunks gated only by producer flags; marks f2/f3 via LDS-counter aggregate.
// Waves 8-15: duty engine — L1-LIF (all blocks, half row) front-loaded,
//   marks f1; L3 blocks' duty waves 0-1 then run wave-local out-scan.
__global__ __launch_bounds__(1024) void snn_persist(
    const unsigned short* __restrict__ cur1,
    const float* __restrict__ W2, const float* __restrict__ b2,
    const float* __restrict__ W3, const float* __restrict__ b3,
    const float* __restrict__ Wo, const float* __restrict__ bo,
    unsigned* __restrict__ s1b, unsigned* __restrict__ s2b,
    unsigned* __restrict__ s3b,
    float* __restrict__ outsum,
    unsigned* __restrict__ f1, unsigned* __restrict__ f2,
    unsigned* __restrict__ f3)
{
  __shared__ char bpan[16 * 2048];             // 32KB i8 weight panel
  __shared__ int cntG[NCH];                    // GEMM-wave completion counters
  __shared__ int cntL1[NCH];                   // duty-wave L1 counters

  const int blk = blockIdx.x, tid = threadIdx.x;
  const bool isL2 = blk < 128;
  const int panel = blk & 127;
  const int n0c = panel * 16;
  const float* Wsrc = isL2 ? W2 : W3;
  const float* bias = isL2 ? b2 : b3;

  if (tid < NCH) cntG[tid] = 0;
  else if (tid < 2 * NCH) cntL1[tid - NCH] = 0;

  float scl = 0.f, bv = 0.f;
  if (tid < 512) {
    const int l = tid & 63;
    const int c16 = l & 15, g = l >> 4;
    const int col = n0c + c16;
    // quant pass 1: per-column absmax; shfl reduce across wave
    float mx = 0.f;
    for (int s = 0; s < 32; ++s) {
      int kb = s * 64 + g * 16;
      #pragma unroll
      for (int e = 0; e < 16; ++e)
        mx = fmaxf(mx, fabsf(Wsrc[(size_t)(kb + e) * HH + col]));
    }
    mx = fmaxf(mx, __shfl_xor(mx, 16));
    mx = fmaxf(mx, __shfl_xor(mx, 32));
    scl = mx * (1.f / 127.f);
    const float rsc = (mx > 0.f) ? (127.f / mx) : 0.f;
    bv = bias[col];
    // quant pass 2: fill LDS panel (tid<512 covers all (c, kg))
    {
      int c = tid & 15, kg = tid >> 4;         // kg 0..31
      #pragma unroll
      for (int j = 0; j < 4; ++j) {
        int k16 = kg * 64 + j * 16;
        int4v q = {0, 0, 0, 0};
        #pragma unroll
        for (int e = 0; e < 16; ++e) {
          float v = Wsrc[(size_t)(k16 + e) * HH + col];
          int qi = (int)rintf(v * rsc);
          qi = qi > 127 ? 127 : (qi < -127 ? -127 : qi);
          q[e >> 2] |= (qi & 0xFF) << ((e & 3) * 8);
        }
        *(int4v*)(bpan + c * 2048 + (k16 ^ ((c & 7) << 4))) = q;
      }
    }
  }
  __syncthreads();   // bpan + counters visible to all

  if (tid < 512) {
    // =========== GEMM engine (waves 0-7) ===========
    const int w = tid >> 6, l = tid & 63;
    const int c16 = l & 15, g = l >> 4;
    const int bbase = c16 * 2048 + g * 16;
    const int bswz = (c16 & 7) << 4;
    const int ppos = ((panel >> 5) << 5) + ((panel & 3) << 3) + ((panel >> 2) & 7);
    const int arow = w * 16 + c16;
    const int abyte = arow * 256 + g * 16;
    const unsigned* sinb = isL2 ? s1b : s2b;
    unsigned* soutb = isL2 ? s2b : s3b;
    unsigned* fin = isL2 ? f1 : f2;
    const int nfin = isL2 ? 256 : 128;
    unsigned* fout = isL2 ? f2 : f3;
    f32x4 memb = {0.f, 0.f, 0.f, 0.f};

    for (int tch = 0; tch < NCH; ++tch) {
      waitwave(fin, nfin, (unsigned)(tch + 1));
      int4v A0[4], A1[4];
      LOADN(A0, tch * CHUNK);
      for (int st2 = 0; st2 < CHUNK; st2 += 2) {
        const int t0 = tch * CHUNK + st2;
        STEPB(A0, A1, t0, 1)
        STEPB(A1, A0, t0 + 1, st2 + 1 < CHUNK - 1)
      }
      if (l == 0) {
        __threadfence();                        // drain this wave's stores
        int old = atomicAdd(&cntG[tch], 1);
        if (old == 7)
          __hip_atomic_store(&fout[panel * 32], (unsigned)(tch + 1),
                             __ATOMIC_RELEASE, __HIP_MEMORY_SCOPE_AGENT);
      }
    }
  } else {
    // =========== duty engine (waves 8-15) ===========
    const int dtid = tid - 512;
    const int dw = dtid >> 6;
    const int l1row = panel;
    const int l1colbase = (blk >> 7) * 1024;
    const int l1kap = (blk >> 7) * 64 + (dtid >> 3);
    const int l1pos = (l1kap & ~31) + ((l1kap & 3) << 3) + ((l1kap >> 2) & 7);
    float m1a = 0.f, m1b = 0.f;

    // L1-LIF: all 5 chunks front-loaded
    for (int p = 0; p < NCH; ++p) {
      #pragma unroll
      for (int half = 0; half < 2; ++half) {
        unsigned cw[10];
        #pragma unroll
        for (int st = 0; st < 10; ++st) {
          int t = p * CHUNK + half * 10 + st;
          cw[st] = *((const unsigned*)(cur1 +
                     ((size_t)t * BB + l1row) * HH + l1colbase) + dtid);
        }
        #pragma unroll
        for (int st = 0; st < 10; ++st) {
          int t = p * CHUNK + half * 10 + st;
          float c0 = bf2f((unsigned short)(cw[st] & 0xFFFF));
          float c1 = bf2f((unsigned short)(cw[st] >> 16));
          float mn0 = 0.9f * m1a + c0 - ((m1a > 1.f) ? 1.f : 0.f);
          float mn1 = 0.9f * m1b + c1 - ((m1b > 1.f) ? 1.f : 0.f);
          m1a = mn0; m1b = mn1;
          unsigned v = (mn0 > 1.f ? 1u : 0u) | (mn1 > 1.f ? 2u : 0u);
          v |= ((unsigned)__shfl_xor((int)v, 1)) << 2;
          v |= ((unsigned)__shfl_xor((int)v, 2)) << 4;
          v |= ((unsigned)__shfl_xor((int)v, 4)) << 8;
          if ((dtid & 7) == 0) {
            unsigned short* so = (unsigned short*)(s1b + (size_t)t * SLOTW)
                                 + l1row * 128;
            so[l1pos] = (unsigned short)v;
          }
        }
      }
      if ((dtid & 63) == 0) {
        __threadfence();
        int old = atomicAdd(&cntL1[p], 1);
        if (old == 7)
          __hip_atomic_store(&f1[blk * 32], (unsigned)(p + 1),
                             __ATOMIC_RELEASE, __HIP_MEMORY_SCOPE_AGENT);
      }
    }

    // out-layer wave-local sparse scan: L3 blocks, duty waves 0-1
    if (!isL2 && dw < 2) {
      const int r = blk - 128;
      const int lane = dtid & 63;
      const int cbase = dw * 50;
      const int myc = cbase + lane;             // class (lane < 50)
      const float boc = (lane < 50 && myc < CC) ? bo[myc] : 0.f;
      float memo = 0.f, osumo = 0.f;
      for (int oc = 0; oc < NCH; ++oc) {
        waitwave(f3, 128, (unsigned)(oc + 1));
        #pragma unroll 1
        for (int st = 0; st < CHUNK; ++st) {
          int t = oc * CHUNK + st;
          unsigned wv = s3b[(size_t)t * SLOTW + r * 64 + lane];  // word `lane`
          unsigned long long m = __ballot((int)(wv != 0u));
          float curv = boc;
          while (m) {
            int wd = (int)__ffsll((long long)m) - 1; m &= m - 1;
            unsigned wv2 = (unsigned)__shfl((int)wv, wd);
            #pragma unroll
            for (int hf = 0; hf < 2; ++hf) {
              unsigned hv = hf ? (wv2 >> 16) : (wv2 & 0xFFFFu);
              int P = wd * 2 + hf;
              int kap = ((P >> 5) << 5) + ((P & 7) << 2) + ((P >> 3) & 3);
              while (hv) {
                int b = (int)__ffs(hv) - 1; hv &= hv - 1;
                if (lane < 50) curv += Wo[(size_t)(kap * 16 + b) * CC + myc];
              }
            }
          }
          float mo = memo;
          float mn = 0.9f * mo + curv - ((mo > 1.f) ? 1.f : 0.f);
          memo = mn;
          if (mn > 1.f) osumo += 1.f;
        }
      }
      if (lane < 50) outsum[r * CC + myc] = osumo;
    }
  }
}

extern "C" void kernel_launch(void* const* d_in, const int* in_sizes, int n_in,
                              void* d_out, int out_size, void* d_ws, size_t ws_size,
                              hipStream_t stream)
{
  const float* x  = (const float*)d_in[0];
  const float* W1 = (const float*)d_in[1];
  const float* b1 = (const float*)d_in[2];
  const float* W2 = (const float*)d_in[3];
  const float* b2 = (const float*)d_in[4];
  const float* W3 = (const float*)d_in[5];
  const float* b3 = (const float*)d_in[6];
  const float* Wo = (const float*)d_in[7];
  const float* bo = (const float*)d_in[8];
  float* out = (float*)d_out;

  // ws layout
  unsigned* flags = (unsigned*)d_ws;                       // 16384 u32 region
  unsigned* f1 = flags;                                    // 256 x stride32
  unsigned* f2 = flags + 8192;                             // 128 x stride32
  unsigned* f3 = flags + 12288;                            // 128 x stride32
  unsigned* s1b = flags + 16384;                           // TT*SLOTW each
  unsigned* s2b = s1b + (size_t)TT * SLOTW;
  unsigned* s3b = s2b + (size_t)TT * SLOTW;
  unsigned short* Wt1 = (unsigned short*)(s3b + (size_t)TT * SLOTW);  // 2048^2
  unsigned short* cur1 = Wt1 + (size_t)HH * HH;            // 12800 x 2048 bf16
  unsigned short* xb = cur1 + (size_t)TT * BB * HH;        // 12800 x 2048 bf16
  size_t need_xb = (size_t)((char*)(xb + (size_t)TT * BB * HH) - (char*)d_ws);

  hipLaunchKernelGGL(init_kernel, dim3(32), dim3(256), 0, stream, flags, 16384);
  hipLaunchKernelGGL(transpose_cvt, dim3(64, 64), dim3(32, 8), 0, stream, W1, Wt1);
  if (ws_size >= need_xb) {
    long n8 = (long)TT * BB * HH / 8;
    hipLaunchKernelGGL(cvt_x, dim3((unsigned)((n8 + 511) / 512)), dim3(512),
                       0, stream, x, xb, n8);
    hipLaunchKernelGGL(gemm_big_bf16, dim3(HH / 64, (TT * BB) / 128), dim3(256),
                       0, stream, xb, Wt1, b1, cur1);
  } else {
    hipLaunchKernelGGL(gemm_big_f32, dim3(HH / 64, (TT * BB) / 128), dim3(256),
                       0, stream, x, Wt1, b1, cur1);
  }
  hipLaunchKernelGGL(snn_persist, dim3(NBLK), dim3(1024), 0, stream,
                     cur1, W2, b2, W3, b3, Wo, bo,
                     s1b, s2b, s3b, out, f1, f2, f3);
}

// Round 18
// 688.424 us; speedup vs baseline: 6.6403x; 6.6180x over previous
//
#include <hip/hip_runtime.h>

typedef short short8 __attribute__((ext_vector_type(8)));
typedef float f32x4 __attribute__((ext_vector_type(4)));
typedef int int4v __attribute__((ext_vector_type(4)));

#define TT 100
#define BB 128
#define HH 2048
#define CC 100
#define NBLK 256
#define CHUNK 20
#define NCH (TT / CHUNK)        // 5 chunks
#define NPHASE (NCH + 3)        // 8 iterations
#define SLOTW 8192              // u32 per step-slot: 128 rows x 64 words

__device__ inline unsigned short f2bf(float f) {
  unsigned u = __float_as_uint(f);
  return (unsigned short)((u + 0x7FFF + ((u >> 16) & 1)) >> 16);  // RNE
}
__device__ inline float bf2f(unsigned short b) {
  return __uint_as_float((unsigned)b << 16);
}

// W[k][n] fp32 (2048x2048) -> Wt[n][k] bf16 bits (for gemm_big / W1 only)
__global__ __launch_bounds__(256) void transpose_cvt(
    const float* __restrict__ W, unsigned short* __restrict__ Wt)
{
  __shared__ float t[32][33];
  int n0 = blockIdx.x * 32, k0 = blockIdx.y * 32;
  int tx = threadIdx.x, ty = threadIdx.y;   // (32,8)
  #pragma unroll
  for (int j = 0; j < 4; ++j)
    t[ty + 8 * j][tx] = W[(size_t)(k0 + ty + 8 * j) * HH + n0 + tx];
  __syncthreads();
  #pragma unroll
  for (int j = 0; j < 4; ++j)
    Wt[(size_t)(n0 + ty + 8 * j) * HH + k0 + tx] = f2bf(t[tx][ty + 8 * j]);
}

// x fp32 -> bf16 (row-major, same layout)
__global__ __launch_bounds__(512) void cvt_x(
    const float* __restrict__ x, unsigned short* __restrict__ xb, long n8)
{
  long i = (long)blockIdx.x * blockDim.x + threadIdx.x;
  if (i >= n8) return;
  const float4* p = (const float4*)x + i * 2;
  float4 a = p[0], b = p[1];
  short8 pv;
  pv[0] = (short)f2bf(a.x); pv[1] = (short)f2bf(a.y);
  pv[2] = (short)f2bf(a.z); pv[3] = (short)f2bf(a.w);
  pv[4] = (short)f2bf(b.x); pv[5] = (short)f2bf(b.y);
  pv[6] = (short)f2bf(b.z); pv[7] = (short)f2bf(b.w);
  *(short8*)(xb + i * 8) = pv;
}

// Hoisted layer-1 GEMM, A already bf16: cur1 = xb @ W1 + b1 (bf16 out).
__global__ __launch_bounds__(256) void gemm_big_bf16(
    const unsigned short* __restrict__ Ab, const unsigned short* __restrict__ Wt,
    const float* __restrict__ bias, unsigned short* __restrict__ cur)
{
  __shared__ unsigned short As[128 * 128];   // 32KB
  __shared__ unsigned short Bs[64 * 128];    // 16KB
  const int tid = threadIdx.x;
  const int w = tid >> 6, l = tid & 63;
  const int wm = w & 1, wn = w >> 1;
  const int c16 = l & 15, g = l >> 4;
  const int n0 = blockIdx.x * 64, m0 = blockIdx.y * 128;
  f32x4 acc[4][2] = {};

  for (int k0 = 0; k0 < 2048; k0 += 128) {
    #pragma unroll
    for (int i = 0; i < 8; ++i) {
      int gg = tid + i * 256;
      int r = gg >> 4, gi = gg & 15;
      int kb = (gi * 16) ^ ((r & 7) << 4);
      const char* src = (const char*)(Ab + (size_t)(m0 + r) * HH + k0) + kb;
      *(int4v*)((char*)As + r * 256 + kb) = *(const int4v*)src;
    }
    #pragma unroll
    for (int i = 0; i < 4; ++i) {
      int gg = tid + i * 256;
      int r = gg >> 4, gi = gg & 15;
      int kb = (gi * 16) ^ ((r & 7) << 4);
      const char* bsrc = (const char*)(Wt + (size_t)(n0 + r) * HH + k0) + kb;
      *(int4v*)((char*)Bs + r * 256 + kb) = *(const int4v*)bsrc;
    }
    __syncthreads();
    #pragma unroll
    for (int kk = 0; kk < 4; ++kk) {
      int koff = (kk * 4 + g) * 16;
      short8 a[4], b[2];
      #pragma unroll
      for (int mi = 0; mi < 4; ++mi) {
        int mr = wm * 64 + mi * 16 + c16;
        a[mi] = *(short8*)((char*)As + mr * 256 + (koff ^ ((mr & 7) << 4)));
      }
      #pragma unroll
      for (int ni = 0; ni < 2; ++ni) {
        int nr = wn * 32 + ni * 16 + c16;
        b[ni] = *(short8*)((char*)Bs + nr * 256 + (koff ^ ((nr & 7) << 4)));
      }
      #pragma unroll
      for (int mi = 0; mi < 4; ++mi)
        #pragma unroll
        for (int ni = 0; ni < 2; ++ni)
          acc[mi][ni] = __builtin_amdgcn_mfma_f32_16x16x32_bf16(
              a[mi], b[ni], acc[mi][ni], 0, 0, 0);
    }
    __syncthreads();
  }
  #pragma unroll
  for (int mi = 0; mi < 4; ++mi)
    #pragma unroll
    for (int ni = 0; ni < 2; ++ni) {
      int col = n0 + wn * 32 + ni * 16 + c16;
      int rbase = m0 + wm * 64 + mi * 16 + g * 4;
      float bv = bias[col];
      #pragma unroll
      for (int j = 0; j < 4; ++j)
        cur[(size_t)(rbase + j) * HH + col] = f2bf(acc[mi][ni][j] + bv);
    }
}

// Fallback (ws too small for xb): fp32 A with inline cvt.
__global__ __launch_bounds__(256) void gemm_big_f32(
    const float* __restrict__ A, const unsigned short* __restrict__ Wt,
    const float* __restrict__ bias, unsigned short* __restrict__ cur)
{
  __shared__ unsigned short As[128 * 128];
  __shared__ unsigned short Bs[64 * 128];
  const int tid = threadIdx.x;
  const int w = tid >> 6, l = tid & 63;
  const int wm = w & 1, wn = w >> 1;
  const int c16 = l & 15, g = l >> 4;
  const int n0 = blockIdx.x * 64, m0 = blockIdx.y * 128;
  f32x4 acc[4][2] = {};

  for (int k0 = 0; k0 < 2048; k0 += 128) {
    #pragma unroll
    for (int i = 0; i < 8; ++i) {
      int gg = tid + i * 256;
      int r = gg >> 4, gi = gg & 15;
      int kb = (gi * 16) ^ ((r & 7) << 4);
      const float* src = A + (size_t)(m0 + r) * HH + k0 + (kb >> 1);
      float4 f0 = *(const float4*)src, f1 = *(const float4*)(src + 4);
      short8 pv;
      pv[0] = (short)f2bf(f0.x); pv[1] = (short)f2bf(f0.y);
      pv[2] = (short)f2bf(f0.z); pv[3] = (short)f2bf(f0.w);
      pv[4] = (short)f2bf(f1.x); pv[5] = (short)f2bf(f1.y);
      pv[6] = (short)f2bf(f1.z); pv[7] = (short)f2bf(f1.w);
      *(int4v*)((char*)As + r * 256 + kb) = *(int4v*)&pv;
    }
    #pragma unroll
    for (int i = 0; i < 4; ++i) {
      int gg = tid + i * 256;
      int r = gg >> 4, gi = gg & 15;
      int kb = (gi * 16) ^ ((r & 7) << 4);
      const char* bsrc = (const char*)(Wt + (size_t)(n0 + r) * HH + k0) + kb;
      *(int4v*)((char*)Bs + r * 256 + kb) = *(const int4v*)bsrc;
    }
    __syncthreads();
    #pragma unroll
    for (int kk = 0; kk < 4; ++kk) {
      int koff = (kk * 4 + g) * 16;
      short8 a[4], b[2];
      #pragma unroll
      for (int mi = 0; mi < 4; ++mi) {
        int mr = wm * 64 + mi * 16 + c16;
        a[mi] = *(short8*)((char*)As + mr * 256 + (koff ^ ((mr & 7) << 4)));
      }
      #pragma unroll
      for (int ni = 0; ni < 2; ++ni) {
        int nr = wn * 32 + ni * 16 + c16;
        b[ni] = *(short8*)((char*)Bs + nr * 256 + (koff ^ ((nr & 7) << 4)));
      }
      #pragma unroll
      for (int mi = 0; mi < 4; ++mi)
        #pragma unroll
        for (int ni = 0; ni < 2; ++ni)
          acc[mi][ni] = __builtin_amdgcn_mfma_f32_16x16x32_bf16(
              a[mi], b[ni], acc[mi][ni], 0, 0, 0);
    }
    __syncthreads();
  }
  #pragma unroll
  for (int mi = 0; mi < 4; ++mi)
    #pragma unroll
    for (int ni = 0; ni < 2; ++ni) {
      int col = n0 + wn * 32 + ni * 16 + c16;
      int rbase = m0 + wm * 64 + mi * 16 + g * 4;
      float bv = bias[col];
      #pragma unroll
      for (int j = 0; j < 4; ++j)
        cur[(size_t)(rbase + j) * HH + col] = f2bf(acc[mi][ni][j] + bv);
    }
}

__global__ void init_kernel(unsigned* flags, int n)
{
  int i = blockIdx.x * blockDim.x + threadIdx.x;
  int stride = gridDim.x * blockDim.x;
  for (int j = i; j < n; j += stride) flags[j] = 0u;
}

// ---- dataflow sync primitives (proven orderings, bounded spins) ----
__device__ inline void markflag(unsigned* f, int idx, unsigned val)
{
  __syncthreads();
  if (threadIdx.x == 0) {
    __threadfence();
    __hip_atomic_store(&f[idx * 32], val, __ATOMIC_RELEASE,
                       __HIP_MEMORY_SCOPE_AGENT);
  }
}
__device__ inline void waitall(unsigned* f, int n, unsigned val)
{
  if (threadIdx.x < n) {
    int guard = 0;
    while (__hip_atomic_load(&f[threadIdx.x * 32], __ATOMIC_ACQUIRE,
                             __HIP_MEMORY_SCOPE_AGENT) < val) {
      __builtin_amdgcn_s_sleep(2);
      if (++guard > (1 << 22)) break;   // fail loud (wrong absmax), never hang
    }
  }
  __syncthreads();
}

// ---- macro-expanded step body; B fragments from LDS; dual accumulator ----
#define MM(WORD, HF, SIDX, ACCV) { \
    unsigned h_ = (HF) ? ((unsigned)(WORD) >> 16) : ((unsigned)(WORD) & 0xFFFFu); \
    int4v af_; \
    af_[0] = (int)(((h_ & 15u) * 0x204081u) & 0x01010101u); \
    af_[1] = (int)((((h_ >> 4) & 15u) * 0x204081u) & 0x01010101u); \
    af_[2] = (int)((((h_ >> 8) & 15u) * 0x204081u) & 0x01010101u); \
    af_[3] = (int)(((h_ >> 12) * 0x204081u) & 0x01010101u); \
    int4v bq_ = *(const int4v*)(bpan + bbase + (((SIDX) * 64) ^ bswz)); \
    ACCV = __builtin_amdgcn_mfma_i32_16x16x64_i8(af_, bq_, ACCV, 0, 0, 0); }

#define STEP8(ACV, CH, ACCV) \
    MM(ACV[CH][0], 0, CH * 8 + 0, ACCV) MM(ACV[CH][0], 1, CH * 8 + 1, ACCV) \
    MM(ACV[CH][1], 0, CH * 8 + 2, ACCV) MM(ACV[CH][1], 1, CH * 8 + 3, ACCV) \
    MM(ACV[CH][2], 0, CH * 8 + 4, ACCV) MM(ACV[CH][2], 1, CH * 8 + 5, ACCV) \
    MM(ACV[CH][3], 0, CH * 8 + 6, ACCV) MM(ACV[CH][3], 1, CH * 8 + 7, ACCV)

#define LOADN(AN, TN) { \
    const char* sb_ = (const char*)(sinb + (size_t)(TN) * SLOTW); \
    AN[0] = *(const int4v*)(sb_ + abyte + 0 * 64); \
    AN[1] = *(const int4v*)(sb_ + abyte + 1 * 64); \
    AN[2] = *(const int4v*)(sb_ + abyte + 2 * 64); \
    AN[3] = *(const int4v*)(sb_ + abyte + 3 * 64); }

#define STEPB(AC, AN, T, DOPRE) { \
    if (DOPRE) LOADN(AN, (T) + 1); \
    int4v acc0_ = {0, 0, 0, 0}, acc1_ = {0, 0, 0, 0}; \
    STEP8(AC, 0, acc0_) STEP8(AC, 1, acc0_) \
    STEP8(AC, 2, acc1_) STEP8(AC, 3, acc1_) \
    int4v accs_ = acc0_ + acc1_; \
    unsigned long long bal0_, bal1_, bal2_, bal3_; \
    { float cv_ = (float)accs_[0] * scl + bv, mo_ = memb[0]; \
      float mn_ = 0.9f * mo_ + cv_ - ((mo_ > 1.f) ? 1.f : 0.f); \
      memb[0] = mn_; bal0_ = __ballot((int)(mn_ > 1.f)); } \
    { float cv_ = (float)accs_[1] * scl + bv, mo_ = memb[1]; \
      float mn_ = 0.9f * mo_ + cv_ - ((mo_ > 1.f) ? 1.f : 0.f); \
      memb[1] = mn_; bal1_ = __ballot((int)(mn_ > 1.f)); } \
    { float cv_ = (float)accs_[2] * scl + bv, mo_ = memb[2]; \
      float mn_ = 0.9f * mo_ + cv_ - ((mo_ > 1.f) ? 1.f : 0.f); \
      memb[2] = mn_; bal2_ = __ballot((int)(mn_ > 1.f)); } \
    { float cv_ = (float)accs_[3] * scl + bv, mo_ = memb[3]; \
      float mn_ = 0.9f * mo_ + cv_ - ((mo_ > 1.f) ? 1.f : 0.f); \
      memb[3] = mn_; bal3_ = __ballot((int)(mn_ > 1.f)); } \
    if (c16 == 0) { \
      unsigned short* so_ = (unsigned short*)(soutb + (size_t)(T) * SLOTW); \
      int rb_ = w * 16 + g * 4; \
      so_[(rb_ + 0) * 128 + ppos] = (unsigned short)((bal0_ >> (g * 16)) & 0xFFFFull); \
      so_[(rb_ + 1) * 128 + ppos] = (unsigned short)((bal1_ >> (g * 16)) & 0xFFFFull); \
      so_[(rb_ + 2) * 128 + ppos] = (unsigned short)((bal2_ >> (g * 16)) & 0xFFFFull); \
      so_[(rb_ + 3) * 128 + ppos] = (unsigned short)((bal3_ >> (g * 16)) & 0xFFFFull); \
    } }

// Persistent SNN: 256 blocks x 512 thr (8 waves).
// GEMM: blk<128 layer2, blk>=128 layer3 (16-col panel each, i8 in 32KB LDS).
// L1-LIF duty: ALL blocks — row = blk&127, column half = (blk>>7)*1024.
// Out-layer sparse scan: L3 blocks, row blk-128.
// DATAFLOW SYNC: no global barrier. f1[256] = L1 chunks done, f2[128] = L2,
// f3[128] = L3 (value = chunk+1). Consumers waitall their producer set only;
// slots are per-step so there are no WAR hazards — fast blocks run ahead.
__global__ __launch_bounds__(512, 1) void snn_persist(
    const unsigned short* __restrict__ cur1,
    const float* __restrict__ W2, const float* __restrict__ b2,
    const float* __restrict__ W3, const float* __restrict__ b3,
    const float* __restrict__ Wo, const float* __restrict__ bo,
    unsigned* __restrict__ s1b, unsigned* __restrict__ s2b,
    unsigned* __restrict__ s3b,
    float* __restrict__ outsum,
    unsigned* __restrict__ f1, unsigned* __restrict__ f2,
    unsigned* __restrict__ f3)
{
  __shared__ char bpan[16 * 2048];             // 32KB i8 weight panel
  __shared__ unsigned sow[CHUNK * 64];         // out-scan row bits (5KB)
  __shared__ unsigned long long swm[CHUNK];    // nonzero-word masks

  const int blk = blockIdx.x, tid = threadIdx.x;
  const int w = tid >> 6, l = tid & 63;
  const int c16 = l & 15, g = l >> 4;
  const bool isL2 = blk < 128;
  const int panel = blk & 127;
  const int n0c = panel * 16;
  const float* Wsrc = isL2 ? W2 : W3;
  const float* bias = isL2 ? b2 : b3;
  const int col = n0c + c16;

  // ---- quant pass 1: per-column absmax; reduce across g via shfl (no LDS)
  float mx = 0.f;
  for (int s = 0; s < 32; ++s) {
    int kb = s * 64 + g * 16;
    #pragma unroll
    for (int e = 0; e < 16; ++e)
      mx = fmaxf(mx, fabsf(Wsrc[(size_t)(kb + e) * HH + col]));
  }
  mx = fmaxf(mx, __shfl_xor(mx, 16));
  mx = fmaxf(mx, __shfl_xor(mx, 32));
  const float scl = mx * (1.f / 127.f);
  const float rsc = (mx > 0.f) ? (127.f / mx) : 0.f;
  const float bv = bias[col];

  // ---- quant pass 2: fill LDS panel. thread -> (col = tid&15, kg = tid>>4).
  {
    int c = tid & 15, kg = tid >> 4;           // kg 0..31, covers 64 k each
    #pragma unroll
    for (int j = 0; j < 4; ++j) {
      int k16 = kg * 64 + j * 16;
      int4v q = {0, 0, 0, 0};
      #pragma unroll
      for (int e = 0; e < 16; ++e) {
        float v = Wsrc[(size_t)(k16 + e) * HH + col];
        int qi = (int)rintf(v * rsc);
        qi = qi > 127 ? 127 : (qi < -127 ? -127 : qi);
        q[e >> 2] |= (qi & 0xFF) << ((e & 3) * 8);
      }
      *(int4v*)(bpan + c * 2048 + (k16 ^ ((c & 7) << 4))) = q;
    }
  }
  __syncthreads();

  const int bbase = c16 * 2048 + g * 16;
  const int bswz = (c16 & 7) << 4;

  const int ppos = ((panel >> 5) << 5) + ((panel & 3) << 3) + ((panel >> 2) & 7);
  const int arow = w * 16 + c16;
  const int abyte = arow * 256 + g * 16;

  const int l1row = panel;
  const int l1colbase = (blk >> 7) * 1024;
  const int l1kap = (blk >> 7) * 64 + (tid >> 3);
  const int l1pos = (l1kap & ~31) + ((l1kap & 3) << 3) + ((l1kap >> 2) & 7);

  float m1a = 0.f, m1b = 0.f;
  f32x4 memb = {0.f, 0.f, 0.f, 0.f};
  float memo = 0.f, osumo = 0.f;
  const float boc = (!isL2 && tid < CC) ? bo[tid] : 0.f;

  for (int p = 0; p < NPHASE; ++p) {
    // ---- L1-LIF duty (ALL blocks, half row each): chunk p; mark f1
    if (p < NCH) {
      #pragma unroll
      for (int half = 0; half < 2; ++half) {
        unsigned cw[10];
        #pragma unroll
        for (int st = 0; st < 10; ++st) {
          int t = p * CHUNK + half * 10 + st;
          cw[st] = *((const unsigned*)(cur1 +
                     ((size_t)t * BB + l1row) * HH + l1colbase) + tid);
        }
        #pragma unroll
        for (int st = 0; st < 10; ++st) {
          int t = p * CHUNK + half * 10 + st;
          float c0 = bf2f((unsigned short)(cw[st] & 0xFFFF));
          float c1 = bf2f((unsigned short)(cw[st] >> 16));
          float mn0 = 0.9f * m1a + c0 - ((m1a > 1.f) ? 1.f : 0.f);
          float mn1 = 0.9f * m1b + c1 - ((m1b > 1.f) ? 1.f : 0.f);
          m1a = mn0; m1b = mn1;
          unsigned v = (mn0 > 1.f ? 1u : 0u) | (mn1 > 1.f ? 2u : 0u);
          v |= ((unsigned)__shfl_xor((int)v, 1)) << 2;
          v |= ((unsigned)__shfl_xor((int)v, 2)) << 4;
          v |= ((unsigned)__shfl_xor((int)v, 4)) << 8;
          if ((tid & 7) == 0) {
            unsigned short* so = (unsigned short*)(s1b + (size_t)t * SLOTW)
                                 + l1row * 128;
            so[l1pos] = (unsigned short)v;
          }
        }
      }
      markflag(f1, blk, (unsigned)(p + 1));
    }

    if (isL2) {
      // ---- L2 GEMM duty: chunk p-1; needs all f1 >= p; marks f2
      int tch = p - 1;
      if (tch >= 0 && tch < NCH) {
        waitall(f1, 256, (unsigned)(tch + 1));
        const unsigned* sinb = s1b;
        unsigned* soutb = s2b;
        int4v AA[4], AB[4];
        {
          int4v* A0 = AA; int4v* A1 = AB;
          (void)A0; (void)A1;
        }
        int4v A0[4], A1[4];
        LOADN(A0, tch * CHUNK);
        for (int st2 = 0; st2 < CHUNK; st2 += 2) {
          const int t0 = tch * CHUNK + st2;
          STEPB(A0, A1, t0, 1)
          STEPB(A1, A0, t0 + 1, st2 + 1 < CHUNK - 1)
        }
        markflag(f2, panel, (unsigned)(tch + 1));
      }
    } else {
      // ---- L3 GEMM duty: chunk p-2; needs all f2 >= p-1; marks f3
      int tch = p - 2;
      if (tch >= 0 && tch < NCH) {
        waitall(f2, 128, (unsigned)(tch + 1));
        const unsigned* sinb = s2b;
        unsigned* soutb = s3b;
        int4v A0[4], A1[4];
        LOADN(A0, tch * CHUNK);
        for (int st2 = 0; st2 < CHUNK; st2 += 2) {
          const int t0 = tch * CHUNK + st2;
          STEPB(A0, A1, t0, 1)
          STEPB(A1, A0, t0 + 1, st2 + 1 < CHUNK - 1)
        }
        markflag(f3, panel, (unsigned)(tch + 1));
      }
      // ---- out-layer sparse scan duty: chunk p-3; needs all f3 >= p-2
      int oc = p - 3;
      if (oc >= 0 && oc < NCH) {
        waitall(f3, 128, (unsigned)(oc + 1));
        int r = blk - 128;
        for (int i = tid; i < CHUNK * 64; i += 512)
          sow[i] = s3b[(size_t)(oc * CHUNK + (i >> 6)) * SLOTW + r * 64 + (i & 63)];
        __syncthreads();
        if (tid < CHUNK) {
          unsigned long long m = 0;
          for (int wd = 0; wd < 64; ++wd)
            if (sow[tid * 64 + wd]) m |= 1ull << wd;
          swm[tid] = m;
        }
        __syncthreads();
        if (tid < CC) {
          #pragma unroll 1
          for (int st = 0; st < CHUNK; ++st) {
            float curv = boc;
            unsigned long long m = swm[st];
            while (m) {
              int wd = (int)__ffsll((long long)m) - 1; m &= m - 1;
              unsigned wv2 = sow[st * 64 + wd];
              #pragma unroll
              for (int hf = 0; hf < 2; ++hf) {
                unsigned hv = hf ? (wv2 >> 16) : (wv2 & 0xFFFFu);
                int P = wd * 2 + hf;
                int kap = ((P >> 5) << 5) + ((P & 7) << 2) + ((P >> 3) & 3);
                while (hv) {
                  int b = (int)__ffs(hv) - 1; hv &= hv - 1;
                  curv += Wo[(size_t)(kap * 16 + b) * CC + tid];
                }
              }
            }
            float mo = memo;
            float mn = 0.9f * mo + curv - ((mo > 1.f) ? 1.f : 0.f);
            memo = mn;
            if (mn > 1.f) osumo += 1.f;
          }
        }
        __syncthreads();
      }
    }
  }

  if (!isL2 && tid < CC)
    outsum[(blk - 128) * CC + tid] = osumo;
}

extern "C" void kernel_launch(void* const* d_in, const int* in_sizes, int n_in,
                              void* d_out, int out_size, void* d_ws, size_t ws_size,
                              hipStream_t stream)
{
  const float* x  = (const float*)d_in[0];
  const float* W1 = (const float*)d_in[1];
  const float* b1 = (const float*)d_in[2];
  const float* W2 = (const float*)d_in[3];
  const float* b2 = (const float*)d_in[4];
  const float* W3 = (const float*)d_in[5];
  const float* b3 = (const float*)d_in[6];
  const float* Wo = (const float*)d_in[7];
  const float* bo = (const float*)d_in[8];
  float* out = (float*)d_out;

  // ws layout
  unsigned* flags = (unsigned*)d_ws;                       // 16384 u32 region
  unsigned* f1 = flags;                                    // 256 x stride32
  unsigned* f2 = flags + 8192;                             // 128 x stride32
  unsigned* f3 = flags + 12288;                            // 128 x stride32
  unsigned* s1b = flags + 16384;                           // TT*SLOTW each
  unsigned* s2b = s1b + (size_t)TT * SLOTW;
  unsigned* s3b = s2b + (size_t)TT * SLOTW;
  unsigned short* Wt1 = (unsigned short*)(s3b + (size_t)TT * SLOTW);  // 2048^2
  unsigned short* cur1 = Wt1 + (size_t)HH * HH;            // 12800 x 2048 bf16
  unsigned short* xb = cur1 + (size_t)TT * BB * HH;        // 12800 x 2048 bf16
  size_t need_xb = (size_t)((char*)(xb + (size_t)TT * BB * HH) - (char*)d_ws);

  hipLaunchKernelGGL(init_kernel, dim3(32), dim3(256), 0, stream, flags, 16384);
  hipLaunchKernelGGL(transpose_cvt, dim3(64, 64), dim3(32, 8), 0, stream, W1, Wt1);
  if (ws_size >= need_xb) {
    long n8 = (long)TT * BB * HH / 8;
    hipLaunchKernelGGL(cvt_x, dim3((unsigned)((n8 + 511) / 512)), dim3(512),
                       0, stream, x, xb, n8);
    hipLaunchKernelGGL(gemm_big_bf16, dim3(HH / 64, (TT * BB) / 128), dim3(256),
                       0, stream, xb, Wt1, b1, cur1);
  } else {
    hipLaunchKernelGGL(gemm_big_f32, dim3(HH / 64, (TT * BB) / 128), dim3(256),
                       0, stream, x, Wt1, b1, cur1);
  }
  hipLaunchKernelGGL(snn_persist, dim3(NBLK), dim3(512), 0, stream,
                     cur1, W2, b2, W3, b3, Wo, bo,
                     s1b, s2b, s3b, out, f1, f2, f3);
}